// Round 25
// baseline (359.263 us; speedup 1.0000x reference)
//
#include <hip/hip_runtime.h>
#include <math.h>

#define NN 768
#define CSn 384
#define CZn 128
#define Hn 12
#define CONCATn 2112
#define LGS 772   // LDS attention row stride: %4==0 (float4 ok), %32==4 (bank shift/h)

// ---------------------------------------------------------------------------
// K1: UNION dispatch = proj_gemm (blocks 0..863) + biasg (blocks 864..10079).
// proj now DIRECT-WRITES q/kT/v (cols<576, no transform needed); only point
// columns (576..1151) go through compact linG[768][576].
// ---------------------------------------------------------------------------
__global__ __launch_bounds__(256, 4) void projbias_kernel(
    const float* __restrict__ s,
    const float* __restrict__ Wq, const float* __restrict__ bq,
    const float* __restrict__ Wkv, const float* __restrict__ bkv,
    const float* __restrict__ Wqp, const float* __restrict__ bqp,
    const float* __restrict__ Wkvp, const float* __restrict__ bkvp,
    float* __restrict__ q, float* __restrict__ kT, float* __restrict__ v,
    float* __restrict__ linG,
    const float* __restrict__ z, const float* __restrict__ Wb,
    const float* __restrict__ bb, float* __restrict__ bG)
{
    __shared__ float sl[16 * 388];   // proj staging (24.8 KB)
    __shared__ float wbs[1536];      // biasg WbT[12][128] (6 KB)
    const int bid = blockIdx.x;
    const int t = threadIdx.x;

    if (bid < 864) {
        // ---------------- proj part: 16-row x 64-col tile ----------------
        const int rt = bid % 48, ct = bid / 48;
        const int r0 = rt * 16;
        for (int x4 = t; x4 < 1536; x4 += 256) {
            const int r = x4 / 96, c4 = x4 % 96;
            *(float4*)&sl[r * 388 + c4 * 4] = *(const float4*)(s + (size_t)(r0 + r) * CSn + c4 * 4);
        }
        __syncthreads();
        const int c = t & 63, rq = t >> 6;
        const int col = ct * 64 + c;
        const float* Wp; int fout; float bias;
        if (col < 192)      { Wp = Wq + col;         fout = 192; bias = bq[col]; }
        else if (col < 576) { Wp = Wkv + (col-192);  fout = 384; bias = bkv[col-192]; }
        else if (col < 720) { Wp = Wqp + (col-576);  fout = 144; bias = bqp[col-576]; }
        else                { Wp = Wkvp + (col-720); fout = 432; bias = bkvp[col-720]; }
        float a0=bias, a1=bias, a2=bias, a3=bias;
        const float* s0 = sl + (rq*4+0)*388;
        const float* s1 = sl + (rq*4+1)*388;
        const float* s2 = sl + (rq*4+2)*388;
        const float* s3 = sl + (rq*4+3)*388;
        float wA[8], wB[8];
        #pragma unroll
        for (int u = 0; u < 8; ++u) wA[u] = Wp[(size_t)u * fout];
        #pragma unroll 1
        for (int kk = 0; kk < 384; kk += 16) {
            #pragma unroll
            for (int u = 0; u < 8; ++u) wB[u] = Wp[(size_t)(kk + 8 + u) * fout];
            #pragma unroll
            for (int u = 0; u < 8; ++u) {
                const float wv = wA[u];
                a0 += s0[kk+u]*wv; a1 += s1[kk+u]*wv;
                a2 += s2[kk+u]*wv; a3 += s3[kk+u]*wv;
            }
            if (kk + 16 < 384) {
                #pragma unroll
                for (int u = 0; u < 8; ++u) wA[u] = Wp[(size_t)(kk + 16 + u) * fout];
            }
            #pragma unroll
            for (int u = 0; u < 8; ++u) {
                const float wv = wB[u];
                a0 += s0[kk+8+u]*wv; a1 += s1[kk+8+u]*wv;
                a2 += s2[kk+8+u]*wv; a3 += s3[kk+8+u]*wv;
            }
        }
        const int rb = r0 + rq*4;
        if (col < 192) {
            q[(size_t)(rb+0)*192 + col] = a0;
            q[(size_t)(rb+1)*192 + col] = a1;
            q[(size_t)(rb+2)*192 + col] = a2;
            q[(size_t)(rb+3)*192 + col] = a3;
        } else if (col < 576) {
            const int tt = col - 192, h = tt >> 5, cc = tt & 31;
            if (cc < 16) {
                float* d = kT + (size_t)(h*16 + cc)*NN + rb;
                d[0] = a0; d[1] = a1; d[2] = a2; d[3] = a3;
            } else {
                const int vc = h*16 + (cc - 16);
                v[(size_t)(rb+0)*192 + vc] = a0;
                v[(size_t)(rb+1)*192 + vc] = a1;
                v[(size_t)(rb+2)*192 + vc] = a2;
                v[(size_t)(rb+3)*192 + vc] = a3;
            }
        } else {
            float* lr = linG + (size_t)rb * 576 + (col - 576);
            lr[0] = a0; lr[576] = a1; lr[2*576] = a2; lr[3*576] = a3;
        }
    } else {
        // ---------------- biasg part: bG[i][h][j] for 64 j ----------------
        const int bb2 = bid - 864;
        const int jt = bb2 % 12, i = bb2 / 12;
        for (int x = t; x < 1536; x += 256) wbs[x] = Wb[(x & 127)*12 + (x >> 7)];
        __syncthreads();

        const int jl = t >> 2, g = t & 3;
        const int j = jt * 64 + jl;
        const float* zr = z + ((size_t)i * NN + j) * CZn + g * 4;
        float4 zv[8];
        #pragma unroll
        for (int u = 0; u < 8; ++u) zv[u] = *(const float4*)(zr + u * 16);   // 8 in flight

        float bh[12];
        #pragma unroll
        for (int h = 0; h < 12; ++h) bh[h] = 0.f;
        #pragma unroll
        for (int u = 0; u < 8; ++u) {
            const float* wb = wbs + u*16 + g*4;
            #pragma unroll
            for (int h = 0; h < 12; ++h) {
                const float4 wv = *(const float4*)(wb + h * 128);   // LDS b128 broadcast
                bh[h] += zv[u].x*wv.x + zv[u].y*wv.y + zv[u].z*wv.z + zv[u].w*wv.w;
            }
        }
        #pragma unroll
        for (int h = 0; h < 12; ++h) {
            bh[h] += __shfl_xor(bh[h], 1);
            bh[h] += __shfl_xor(bh[h], 2);
        }
        float bsel[3];
        #pragma unroll
        for (int hh = 0; hh < 3; ++hh) {
            const float v01 = (g & 1) ? bh[3+hh] : bh[0+hh];
            const float v23 = (g & 1) ? bh[9+hh] : bh[6+hh];
            bsel[hh] = (g & 2) ? v23 : v01;
        }
        float* bgr = bG + (size_t)i * (Hn*NN) + j;
        #pragma unroll
        for (int hh = 0; hh < 3; ++hh) {
            const int h = 3*g + hh;
            bgr[(size_t)h * NN] = 0.5773502691896258f * (bsel[hh] + bb[h]);
        }
    }
}

// ---------------------------------------------------------------------------
// K2: pts_scatter — transform-only.  linG compact [768][576]:
// qp raw at cols 0..143 (x:t, y:48+t, z:96+t); kv pts at 144..575.
// ---------------------------------------------------------------------------
__global__ __launch_bounds__(256) void pts_scatter_kernel(
    const float* __restrict__ linG, const float* __restrict__ rot, const float* __restrict__ trans,
    float* __restrict__ qp, float* __restrict__ kpT, float* __restrict__ vp)
{
    const int i = blockIdx.x, t = threadIdx.x;
    const float* lr = linG + (size_t)i * 576;
    const float R0 = rot[i*9+0], R1 = rot[i*9+1], R2 = rot[i*9+2];
    const float R3 = rot[i*9+3], R4 = rot[i*9+4], R5 = rot[i*9+5];
    const float R6 = rot[i*9+6], R7 = rot[i*9+7], R8 = rot[i*9+8];
    const float T0 = trans[i*3+0], T1 = trans[i*3+1], T2 = trans[i*3+2];
    if (t < 48) {
        const float px = lr[t], py = lr[48 + t], pz = lr[96 + t];
        float* d = qp + (size_t)i*144 + t*3;
        d[0] = R0*px + R1*py + R2*pz + T0;
        d[1] = R3*px + R4*py + R5*pz + T1;
        d[2] = R6*px + R7*py + R8*pz + T2;
    }
    if (t < 144) {
        const float px = lr[144 + t], py = lr[288 + t], pz = lr[432 + t];
        const float gx = R0*px + R1*py + R2*pz + T0;
        const float gy = R3*px + R4*py + R5*pz + T1;
        const float gz = R6*px + R7*py + R8*pz + T2;
        const int h = t / 12, pp = t % 12;
        if (pp < 4) {
            float* d = kpT + (size_t)(h*12 + pp*3)*NN + i;
            d[0] = gx; d[NN] = gy; d[2*NN] = gz;
        } else {
            float* d = vp + (size_t)i*288 + ((h*8) + (pp-4))*3;
            d[0] = gx; d[1] = gy; d[2] = gz;
        }
    }
}

// load/compute macros for mega phase-1 software pipeline (static names only)
#define LOADG(KV, KPV, BGv, MJv, uu) {                                        \
    const int jo_ = (uu) * 64;                                                \
    _Pragma("unroll") for (int c_ = 0; c_ < 16; ++c_)                         \
        KV[c_] = kb[(size_t)c_*NN + jo_];                                     \
    _Pragma("unroll") for (int e_ = 0; e_ < 12; ++e_)                         \
        KPV[e_] = kpb[(size_t)e_*NN + jo_];                                   \
    BGv = bgb[jo_]; MJv = mask[l + jo_]; }

#define COMPG(KV, KPV, BGv, MJv, uu) {                                        \
    float qk_ = 0.f;                                                          \
    _Pragma("unroll") for (int c_ = 0; c_ < 16; ++c_) qk_ += qreg[c_]*KV[c_]; \
    float d2_ = 0.f;                                                          \
    _Pragma("unroll") for (int e_ = 0; e_ < 12; ++e_) {                       \
        const float d_ = qpreg[e_] - KPV[e_]; d2_ += d_*d_; }                 \
    e[uu] = 0.14433756729740643f*qk_ + BGv + coef*d2_                         \
          + 100000.0f*(mi*MJv - 1.0f); }

// ---------------------------------------------------------------------------
// K3: MEGA (r24 champion, byte-identical).
// ---------------------------------------------------------------------------
__global__ __launch_bounds__(256, 3) void mega_kernel(
    const float* __restrict__ mask,
    const float* __restrict__ q, const float* __restrict__ qp,
    const float* __restrict__ kT, const float* __restrict__ kpT,
    const float* __restrict__ bG, const float* __restrict__ head_w,
    const float* __restrict__ z,
    const float* __restrict__ v, const float* __restrict__ vp,
    const float* __restrict__ rot, const float* __restrict__ trans,
    float* __restrict__ cat)
{
    const int i = blockIdx.x, t = threadIdx.x;
    const int w = t >> 6, l = t & 63;
    __shared__ float lg[Hn * LGS];     // 37 KB attention
    __shared__ float qs[192], qps[144], coefS[12];
    __shared__ float pts[288];
    if (t < 192) qs[t] = q[(size_t)i*192 + t];
    if (t < 144) qps[t] = qp[(size_t)i*144 + t];
    if (t < 12) coefS[t] = -0.5f * 0.1360827634879543f * log1pf(expf(head_w[t]));
    __syncthreads();
    const float mi = mask[i];

    // ---- Phase 1: logits + softmax, software-pipelined loads -------------
    #pragma unroll 1
    for (int hh = 0; hh < 3; ++hh) {
        const int h = w*3 + hh;
        float qreg[16], qpreg[12];
        #pragma unroll
        for (int c = 0; c < 16; ++c) qreg[c] = qs[h*16 + c];
        #pragma unroll
        for (int ee = 0; ee < 12; ++ee) qpreg[ee] = qps[h*12 + ee];
        const float coef = coefS[h];
        const float* kb  = kT  + (size_t)(h*16)*NN + l;
        const float* kpb = kpT + (size_t)(h*12)*NN + l;
        const float* bgb = bG + (size_t)i*(Hn*NN) + (size_t)h*NN + l;
        float e[12];
        float kvA[16], kpvA[12], bgA, mjA;
        float kvB[16], kpvB[12], bgB, mjB;
        LOADG(kvA, kpvA, bgA, mjA, 0);
        #pragma unroll
        for (int u = 0; u < 12; u += 2) {
            LOADG(kvB, kpvB, bgB, mjB, u + 1);
            COMPG(kvA, kpvA, bgA, mjA, u);
            if (u + 2 < 12) LOADG(kvA, kpvA, bgA, mjA, u + 2);
            COMPG(kvB, kpvB, bgB, mjB, u + 1);
        }
        float m = -1e30f;
        #pragma unroll
        for (int u = 0; u < 12; ++u) m = fmaxf(m, e[u]);
        #pragma unroll
        for (int off = 32; off > 0; off >>= 1) m = fmaxf(m, __shfl_xor(m, off));
        float ssum = 0.f;
        #pragma unroll
        for (int u = 0; u < 12; ++u) { e[u] = expf(e[u] - m); ssum += e[u]; }
        #pragma unroll
        for (int off = 32; off > 0; off >>= 1) ssum += __shfl_xor(ssum, off);
        const float inv = 1.0f / ssum;
        #pragma unroll
        for (int u = 0; u < 12; ++u) lg[h*LGS + l + u*64] = e[u] * inv;
    }
    __syncthreads();

    // ---- Phase 2: o + o_pt, A/B-pipelined global loads -------------------
    {
        float accA = 0.f;
        const float* srcA; int strA; int hA;
        if (t < 192) { srcA = v + t;          strA = 192; hA = t >> 4; }
        else         { srcA = vp + (t - 192); strA = 288; hA = (t - 192) / 24; }
        const float* arA = lg + hA * LGS;
        {
            float vA[8], vB[8];
            #pragma unroll
            for (int u = 0; u < 8; ++u) vA[u] = srcA[(size_t)u * strA];
            #pragma unroll 1
            for (int jb = 0; jb < NN; jb += 16) {
                #pragma unroll
                for (int u = 0; u < 8; ++u) vB[u] = srcA[(size_t)(jb + 8 + u) * strA];
                #pragma unroll
                for (int u = 0; u < 8; ++u) accA += arA[jb + u] * vA[u];
                if (jb + 16 < NN) {
                    #pragma unroll
                    for (int u = 0; u < 8; ++u) vA[u] = srcA[(size_t)(jb + 16 + u) * strA];
                }
                #pragma unroll
                for (int u = 0; u < 8; ++u) accA += arA[jb + 8 + u] * vB[u];
            }
        }
        float accB = 0.f;
        if (t < 224) {
            const int cB = 64 + t;                 // vp cols 64..287
            const float* srcB = vp + cB;
            const float* arB = lg + (cB / 24) * LGS;
            float vA[8], vB[8];
            #pragma unroll
            for (int u = 0; u < 8; ++u) vA[u] = srcB[(size_t)u * 288];
            #pragma unroll 1
            for (int jb = 0; jb < NN; jb += 16) {
                #pragma unroll
                for (int u = 0; u < 8; ++u) vB[u] = srcB[(size_t)(jb + 8 + u) * 288];
                #pragma unroll
                for (int u = 0; u < 8; ++u) accB += arB[jb + u] * vA[u];
                if (jb + 16 < NN) {
                    #pragma unroll
                    for (int u = 0; u < 8; ++u) vA[u] = srcB[(size_t)(jb + 16 + u) * 288];
                }
                #pragma unroll
                for (int u = 0; u < 8; ++u) accB += arB[jb + 8 + u] * vB[u];
            }
        }
        float* catr = cat + (size_t)i*CONCATn;
        if (t < 192) catr[t] = accA;
        else         pts[t - 192] = accA;
        if (t < 224) pts[64 + t] = accB;
    }
    __syncthreads();

    // ---- Phase 3: frame invert + norms -----------------------------------
    if (t < 96) {
        const float gx = pts[t*3+0] - trans[i*3+0];
        const float gy = pts[t*3+1] - trans[i*3+1];
        const float gz = pts[t*3+2] - trans[i*3+2];
        const float lx = rot[i*9+0]*gx + rot[i*9+3]*gy + rot[i*9+6]*gz;
        const float ly = rot[i*9+1]*gx + rot[i*9+4]*gy + rot[i*9+7]*gz;
        const float lz = rot[i*9+2]*gx + rot[i*9+5]*gy + rot[i*9+8]*gz;
        float* catr = cat + (size_t)i*CONCATn;
        catr[192 + t] = lx;
        catr[288 + t] = ly;
        catr[384 + t] = lz;
        catr[480 + t] = sqrtf(lx*lx + ly*ly + lz*lz + 1e-8f);
    }

    // ---- Phase 4: o_pair, float4 z + 2 j/instr + shfl --------------------
    {
        const int c4 = l & 31, jp = l >> 5;
        const float* zb = z + (size_t)i*NN*CZn + c4*4;
        const float* a0 = lg + (size_t)(3*w + 0)*LGS;
        const float* a1 = lg + (size_t)(3*w + 1)*LGS;
        const float* a2 = lg + (size_t)(3*w + 2)*LGS;
        float x00=0.f,x01=0.f,x02=0.f,x03=0.f;
        float x10=0.f,x11=0.f,x12=0.f,x13=0.f;
        float x20=0.f,x21=0.f,x22=0.f,x23=0.f;
        #pragma unroll 8
        for (int j2 = 0; j2 < 384; ++j2) {
            const int j = 2*j2 + jp;
            const float4 zv = *(const float4*)(zb + (size_t)j*CZn);
            const float A0 = a0[j], A1 = a1[j], A2 = a2[j];   // 2-way LDS broadcast
            x00 += A0*zv.x; x01 += A0*zv.y; x02 += A0*zv.z; x03 += A0*zv.w;
            x10 += A1*zv.x; x11 += A1*zv.y; x12 += A1*zv.z; x13 += A1*zv.w;
            x20 += A2*zv.x; x21 += A2*zv.y; x22 += A2*zv.z; x23 += A2*zv.w;
        }
        x00 += __shfl_xor(x00, 32); x01 += __shfl_xor(x01, 32);
        x02 += __shfl_xor(x02, 32); x03 += __shfl_xor(x03, 32);
        x10 += __shfl_xor(x10, 32); x11 += __shfl_xor(x11, 32);
        x12 += __shfl_xor(x12, 32); x13 += __shfl_xor(x13, 32);
        x20 += __shfl_xor(x20, 32); x21 += __shfl_xor(x21, 32);
        x22 += __shfl_xor(x22, 32); x23 += __shfl_xor(x23, 32);
        if (jp == 0) {
            float* cr = cat + (size_t)i*CONCATn + 576 + c4*4;
            float4 r0; r0.x=x00; r0.y=x01; r0.z=x02; r0.w=x03;
            float4 r1; r1.x=x10; r1.y=x11; r1.z=x12; r1.w=x13;
            float4 r2; r2.x=x20; r2.y=x21; r2.z=x22; r2.w=x23;
            *(float4*)(cr + (size_t)(3*w+0)*CZn) = r0;
            *(float4*)(cr + (size_t)(3*w+1)*CZn) = r1;
            *(float4*)(cr + (size_t)(3*w+2)*CZn) = r2;
        }
    }
}

// ---------------------------------------------------------------------------
// K4: out split-K partials, 4-way + A/B-pipelined W loads.
// Grid (192 rt, 3 ot, 4 qt), 128 thr.  LDS 8.4 KB.
// ---------------------------------------------------------------------------
__global__ __launch_bounds__(128) void outpart_kernel(
    const float* __restrict__ cat, const float* __restrict__ Wout,
    float* __restrict__ pbuf)
{
    const int rt = blockIdx.x;
    const int ot = blockIdx.y;
    const int qt = blockIdx.z;
    __shared__ float cl[4 * 528];     // 8.4 KB
    const int r0 = rt * 4;
    const int kb = qt * 528;
    for (int idx = threadIdx.x; idx < 528; idx += 128) {   // 132 float4/row x 4 rows
        const int r = idx / 132, c4 = idx % 132;
        *(float4*)&cl[r*528 + c4*4] =
            *(const float4*)(cat + (size_t)(r0 + r)*CONCATn + kb + c4*4);
    }
    __syncthreads();
    const int t = threadIdx.x;
    const int r  = t >> 5;
    const int o4 = t & 31;
    const int col = ot * 128 + o4 * 4;
    float4 acc; acc.x = 0.f; acc.y = 0.f; acc.z = 0.f; acc.w = 0.f;
    const float* wp = Wout + (size_t)kb * 384 + col;
    const float* cr = cl + r * 528;
    float4 wA[8], wB[8];
    #pragma unroll
    for (int u = 0; u < 8; ++u) wA[u] = *(const float4*)(wp + (size_t)u * 384);
    #pragma unroll 1
    for (int kk = 0; kk < 528; kk += 16) {
        #pragma unroll
        for (int u = 0; u < 8; ++u)
            wB[u] = *(const float4*)(wp + (size_t)(kk + 8 + u) * 384);
        #pragma unroll
        for (int u = 0; u < 8; ++u) {
            const float cv = cr[kk + u];
            acc.x += cv * wA[u].x; acc.y += cv * wA[u].y;
            acc.z += cv * wA[u].z; acc.w += cv * wA[u].w;
        }
        if (kk + 16 < 528) {
            #pragma unroll
            for (int u = 0; u < 8; ++u)
                wA[u] = *(const float4*)(wp + (size_t)(kk + 16 + u) * 384);
        }
        #pragma unroll
        for (int u = 0; u < 8; ++u) {
            const float cv = cr[kk + 8 + u];
            acc.x += cv * wB[u].x; acc.y += cv * wB[u].y;
            acc.z += cv * wB[u].z; acc.w += cv * wB[u].w;
        }
    }
    *(float4*)(pbuf + ((size_t)qt*NN + r0 + r)*384 + col) = acc;
}

// ---------------------------------------------------------------------------
// K5: out finalize: out = p0+p1+p2+p3 + bias.  Grid 288, 256 thr, float4.
// ---------------------------------------------------------------------------
__global__ __launch_bounds__(256) void outfin_kernel(
    const float* __restrict__ pbuf, const float* __restrict__ bout,
    float* __restrict__ out)
{
    const int idx4 = blockIdx.x * 256 + threadIdx.x;   // 0..73727
    const int Q = NN * 384 / 4;                        // 73728 float4 per partial
    const float4 p0 = ((const float4*)pbuf)[idx4];
    const float4 p1 = ((const float4*)pbuf)[idx4 + Q];
    const float4 p2 = ((const float4*)pbuf)[idx4 + 2*Q];
    const float4 p3 = ((const float4*)pbuf)[idx4 + 3*Q];
    const float4 bo = *(const float4*)(bout + (idx4 % 96) * 4);
    float4 r;
    r.x = p0.x + p1.x + p2.x + p3.x + bo.x;
    r.y = p0.y + p1.y + p2.y + p3.y + bo.y;
    r.z = p0.z + p1.z + p2.z + p3.z + bo.z;
    r.w = p0.w + p1.w + p2.w + p3.w + bo.w;
    ((float4*)out)[idx4] = r;
}

// ---------------------------------------------------------------------------
extern "C" void kernel_launch(void* const* d_in, const int* in_sizes, int n_in,
                              void* d_out, int out_size, void* d_ws, size_t ws_size,
                              hipStream_t stream)
{
    const float* s     = (const float*)d_in[0];
    const float* z     = (const float*)d_in[1];
    const float* rot   = (const float*)d_in[2];
    const float* trans = (const float*)d_in[3];
    const float* mask  = (const float*)d_in[4];
    const float* Wq    = (const float*)d_in[5];
    const float* bq    = (const float*)d_in[6];
    const float* Wkv   = (const float*)d_in[7];
    const float* bkv   = (const float*)d_in[8];
    const float* Wqp   = (const float*)d_in[9];
    const float* bqp   = (const float*)d_in[10];
    const float* Wkvp  = (const float*)d_in[11];
    const float* bkvp  = (const float*)d_in[12];
    const float* Wb    = (const float*)d_in[13];
    const float* bb    = (const float*)d_in[14];
    const float* head_w= (const float*)d_in[15];
    const float* Wout  = (const float*)d_in[16];
    const float* bout  = (const float*)d_in[17];
    float* out = (float*)d_out;

    float* ws    = (float*)d_ws;
    float* q     = ws;                  // 147456  [N][192]
    float* kT    = q     + 147456;      // 147456  [192][N]
    float* qp    = kT    + 147456;      // 110592  [N][144]
    float* kpT   = qp    + 110592;      // 110592  [144][N]
    float* v     = kpT   + 110592;      // 147456  [N][192]
    float* vp    = v     + 147456;      // 221184  [N][288]
    float* cat   = vp    + 221184;      // 1622016
    float* linG  = cat   + 1622016;     // 442368  (compact [768][576] points)
    float* bG    = linG  + 442368;      // 7077888 (28 MB)
    float* pbuf  = bG    + 7077888;     // 1179648 (4x out partials)

    hipLaunchKernelGGL(projbias_kernel, dim3(864 + 12*768), dim3(256), 0, stream,
        s, Wq, bq, Wkv, bkv, Wqp, bqp, Wkvp, bkvp, q, kT, v, linG, z, Wb, bb, bG);
    hipLaunchKernelGGL(pts_scatter_kernel, dim3(768), dim3(256), 0, stream,
        linG, rot, trans, qp, kpT, vp);
    hipLaunchKernelGGL(mega_kernel, dim3(768), dim3(256), 0, stream,
        mask, q, qp, kT, kpT, bG, head_w, z, v, vp, rot, trans, cat);
    hipLaunchKernelGGL(outpart_kernel, dim3(192, 3, 4), dim3(128), 0, stream,
        cat, Wout, pbuf);
    hipLaunchKernelGGL(outfin_kernel, dim3(288), dim3(256), 0, stream,
        pbuf, bout, out);
}

// Round 26
// 352.311 us; speedup vs baseline: 1.0197x; 1.0197x over previous
//
#include <hip/hip_runtime.h>
#include <math.h>

#define NN 768
#define CSn 384
#define CZn 128
#define Hn 12
#define CONCATn 2112
#define LGS 772   // LDS attention row stride: %4==0 (float4 ok), %32==4 (bank shift/h)

// ---------------------------------------------------------------------------
// K1: UNION dispatch = proj_gemm (blocks 0..863) + biasg (blocks 864..10079).
// ---------------------------------------------------------------------------
__global__ __launch_bounds__(256, 4) void projbias_kernel(
    const float* __restrict__ s,
    const float* __restrict__ Wq, const float* __restrict__ bq,
    const float* __restrict__ Wkv, const float* __restrict__ bkv,
    const float* __restrict__ Wqp, const float* __restrict__ bqp,
    const float* __restrict__ Wkvp, const float* __restrict__ bkvp,
    float* __restrict__ linG,
    const float* __restrict__ z, const float* __restrict__ Wb,
    const float* __restrict__ bb, float* __restrict__ bG)
{
    __shared__ float sl[16 * 388];   // proj staging (24.8 KB)
    __shared__ float wbs[1536];      // biasg WbT[12][128] (6 KB)
    const int bid = blockIdx.x;
    const int t = threadIdx.x;

    if (bid < 864) {
        // ---------------- proj part: 16-row x 64-col tile ----------------
        const int rt = bid % 48, ct = bid / 48;
        const int r0 = rt * 16;
        for (int x4 = t; x4 < 1536; x4 += 256) {
            const int r = x4 / 96, c4 = x4 % 96;
            *(float4*)&sl[r * 388 + c4 * 4] = *(const float4*)(s + (size_t)(r0 + r) * CSn + c4 * 4);
        }
        __syncthreads();
        const int c = t & 63, rq = t >> 6;
        const int col = ct * 64 + c;
        const float* Wp; int fout; float bias;
        if (col < 192)      { Wp = Wq + col;         fout = 192; bias = bq[col]; }
        else if (col < 576) { Wp = Wkv + (col-192);  fout = 384; bias = bkv[col-192]; }
        else if (col < 720) { Wp = Wqp + (col-576);  fout = 144; bias = bqp[col-576]; }
        else                { Wp = Wkvp + (col-720); fout = 432; bias = bkvp[col-720]; }
        float a0=bias, a1=bias, a2=bias, a3=bias;
        const float* s0 = sl + (rq*4+0)*388;
        const float* s1 = sl + (rq*4+1)*388;
        const float* s2 = sl + (rq*4+2)*388;
        const float* s3 = sl + (rq*4+3)*388;
        float wA[8], wB[8];
        #pragma unroll
        for (int u = 0; u < 8; ++u) wA[u] = Wp[(size_t)u * fout];
        #pragma unroll 1
        for (int kk = 0; kk < 384; kk += 16) {
            #pragma unroll
            for (int u = 0; u < 8; ++u) wB[u] = Wp[(size_t)(kk + 8 + u) * fout];
            #pragma unroll
            for (int u = 0; u < 8; ++u) {
                const float wv = wA[u];
                a0 += s0[kk+u]*wv; a1 += s1[kk+u]*wv;
                a2 += s2[kk+u]*wv; a3 += s3[kk+u]*wv;
            }
            if (kk + 16 < 384) {
                #pragma unroll
                for (int u = 0; u < 8; ++u) wA[u] = Wp[(size_t)(kk + 16 + u) * fout];
            }
            #pragma unroll
            for (int u = 0; u < 8; ++u) {
                const float wv = wB[u];
                a0 += s0[kk+8+u]*wv; a1 += s1[kk+8+u]*wv;
                a2 += s2[kk+8+u]*wv; a3 += s3[kk+8+u]*wv;
            }
        }
        float* lr = linG + (size_t)(r0 + rq*4) * 1152 + col;
        lr[0] = a0; lr[1152] = a1; lr[2*1152] = a2; lr[3*1152] = a3;
    } else {
        // ---------------- biasg part: bG[i][h][j] for 64 j ----------------
        const int bb2 = bid - 864;
        const int jt = bb2 % 12, i = bb2 / 12;
        for (int x = t; x < 1536; x += 256) wbs[x] = Wb[(x & 127)*12 + (x >> 7)];
        __syncthreads();

        const int jl = t >> 2, g = t & 3;
        const int j = jt * 64 + jl;
        const float* zr = z + ((size_t)i * NN + j) * CZn + g * 4;
        float4 zv[8];
        #pragma unroll
        for (int u = 0; u < 8; ++u) zv[u] = *(const float4*)(zr + u * 16);   // 8 in flight

        float bh[12];
        #pragma unroll
        for (int h = 0; h < 12; ++h) bh[h] = 0.f;
        #pragma unroll
        for (int u = 0; u < 8; ++u) {
            const float* wb = wbs + u*16 + g*4;
            #pragma unroll
            for (int h = 0; h < 12; ++h) {
                const float4 wv = *(const float4*)(wb + h * 128);   // LDS b128 broadcast
                bh[h] += zv[u].x*wv.x + zv[u].y*wv.y + zv[u].z*wv.z + zv[u].w*wv.w;
            }
        }
        #pragma unroll
        for (int h = 0; h < 12; ++h) {
            bh[h] += __shfl_xor(bh[h], 1);
            bh[h] += __shfl_xor(bh[h], 2);
        }
        float bsel[3];
        #pragma unroll
        for (int hh = 0; hh < 3; ++hh) {
            const float v01 = (g & 1) ? bh[3+hh] : bh[0+hh];
            const float v23 = (g & 1) ? bh[9+hh] : bh[6+hh];
            bsel[hh] = (g & 2) ? v23 : v01;
        }
        float* bgr = bG + (size_t)i * (Hn*NN) + j;
        #pragma unroll
        for (int hh = 0; hh < 3; ++hh) {
            const int h = 3*g + hh;
            bgr[(size_t)h * NN] = 0.5773502691896258f * (bsel[hh] + bb[h]);
        }
    }
}

// ---------------------------------------------------------------------------
// K2: scatter linG -> q [N][192], kT [192][768], v [N][192], qp [N][144],
//     kpT [144][768], vp [N][288].
// ---------------------------------------------------------------------------
__global__ __launch_bounds__(256) void scatter_kernel(
    const float* __restrict__ linG, const float* __restrict__ rot, const float* __restrict__ trans,
    float* __restrict__ q, float* __restrict__ kT, float* __restrict__ v,
    float* __restrict__ qp, float* __restrict__ kpT, float* __restrict__ vp)
{
    const int i = blockIdx.x, t = threadIdx.x;
    const float* lr = linG + (size_t)i * 1152;
    if (t < 192) q[(size_t)i*192 + t] = lr[t];
    for (int tt = t; tt < 384; tt += 256) {
        const int h = tt >> 5, cc = tt & 31;
        const float val = lr[192 + tt];
        if (cc < 16) kT[(size_t)(h*16 + cc)*NN + i] = val;
        else         v[(size_t)i*192 + h*16 + (cc-16)] = val;
    }
    const float R0 = rot[i*9+0], R1 = rot[i*9+1], R2 = rot[i*9+2];
    const float R3 = rot[i*9+3], R4 = rot[i*9+4], R5 = rot[i*9+5];
    const float R6 = rot[i*9+6], R7 = rot[i*9+7], R8 = rot[i*9+8];
    const float T0 = trans[i*3+0], T1 = trans[i*3+1], T2 = trans[i*3+2];
    if (t < 48) {
        const float px = lr[576 + t], py = lr[576 + 48 + t], pz = lr[576 + 96 + t];
        float* d = qp + (size_t)i*144 + t*3;
        d[0] = R0*px + R1*py + R2*pz + T0;
        d[1] = R3*px + R4*py + R5*pz + T1;
        d[2] = R6*px + R7*py + R8*pz + T2;
    }
    if (t < 144) {
        const float px = lr[720 + t], py = lr[720 + 144 + t], pz = lr[720 + 288 + t];
        const float gx = R0*px + R1*py + R2*pz + T0;
        const float gy = R3*px + R4*py + R5*pz + T1;
        const float gz = R6*px + R7*py + R8*pz + T2;
        const int h = t / 12, pp = t % 12;
        if (pp < 4) {
            float* d = kpT + (size_t)(h*12 + pp*3)*NN + i;
            d[0] = gx; d[NN] = gy; d[2*NN] = gz;
        } else {
            float* d = vp + (size_t)i*288 + ((h*8) + (pp-4))*3;
            d[0] = gx; d[1] = gy; d[2] = gz;
        }
    }
}

// load/compute macros for mega phase-1 software pipeline (static names only)
#define LOADG(KV, KPV, BGv, MJv, uu) {                                        \
    const int jo_ = (uu) * 64;                                                \
    _Pragma("unroll") for (int c_ = 0; c_ < 16; ++c_)                         \
        KV[c_] = kb[(size_t)c_*NN + jo_];                                     \
    _Pragma("unroll") for (int e_ = 0; e_ < 12; ++e_)                         \
        KPV[e_] = kpb[(size_t)e_*NN + jo_];                                   \
    BGv = bgb[jo_]; MJv = mask[l + jo_]; }

#define COMPG(KV, KPV, BGv, MJv, uu) {                                        \
    float qk_ = 0.f;                                                          \
    _Pragma("unroll") for (int c_ = 0; c_ < 16; ++c_) qk_ += qreg[c_]*KV[c_]; \
    float d2_ = 0.f;                                                          \
    _Pragma("unroll") for (int e_ = 0; e_ < 12; ++e_) {                       \
        const float d_ = qpreg[e_] - KPV[e_]; d2_ += d_*d_; }                 \
    e[uu] = 0.14433756729740643f*qk_ + BGv + coef*d2_                         \
          + 100000.0f*(mi*MJv - 1.0f); }

// ---------------------------------------------------------------------------
// K3: MEGA (champion).  Phases 1,2 A/B-pipelined; phase 4 A/B form.
// ---------------------------------------------------------------------------
__global__ __launch_bounds__(256, 3) void mega_kernel(
    const float* __restrict__ mask,
    const float* __restrict__ q, const float* __restrict__ qp,
    const float* __restrict__ kT, const float* __restrict__ kpT,
    const float* __restrict__ bG, const float* __restrict__ head_w,
    const float* __restrict__ z,
    const float* __restrict__ v, const float* __restrict__ vp,
    const float* __restrict__ rot, const float* __restrict__ trans,
    float* __restrict__ cat)
{
    const int i = blockIdx.x, t = threadIdx.x;
    const int w = t >> 6, l = t & 63;
    __shared__ float lg[Hn * LGS];     // 37 KB attention
    __shared__ float qs[192], qps[144], coefS[12];
    __shared__ float pts[288];
    if (t < 192) qs[t] = q[(size_t)i*192 + t];
    if (t < 144) qps[t] = qp[(size_t)i*144 + t];
    if (t < 12) coefS[t] = -0.5f * 0.1360827634879543f * log1pf(expf(head_w[t]));
    __syncthreads();
    const float mi = mask[i];

    // ---- Phase 1: logits + softmax, software-pipelined loads -------------
    #pragma unroll 1
    for (int hh = 0; hh < 3; ++hh) {
        const int h = w*3 + hh;
        float qreg[16], qpreg[12];
        #pragma unroll
        for (int c = 0; c < 16; ++c) qreg[c] = qs[h*16 + c];
        #pragma unroll
        for (int ee = 0; ee < 12; ++ee) qpreg[ee] = qps[h*12 + ee];
        const float coef = coefS[h];
        const float* kb  = kT  + (size_t)(h*16)*NN + l;
        const float* kpb = kpT + (size_t)(h*12)*NN + l;
        const float* bgb = bG + (size_t)i*(Hn*NN) + (size_t)h*NN + l;
        float e[12];
        float kvA[16], kpvA[12], bgA, mjA;
        float kvB[16], kpvB[12], bgB, mjB;
        LOADG(kvA, kpvA, bgA, mjA, 0);
        #pragma unroll
        for (int u = 0; u < 12; u += 2) {
            LOADG(kvB, kpvB, bgB, mjB, u + 1);
            COMPG(kvA, kpvA, bgA, mjA, u);
            if (u + 2 < 12) LOADG(kvA, kpvA, bgA, mjA, u + 2);
            COMPG(kvB, kpvB, bgB, mjB, u + 1);
        }
        float m = -1e30f;
        #pragma unroll
        for (int u = 0; u < 12; ++u) m = fmaxf(m, e[u]);
        #pragma unroll
        for (int off = 32; off > 0; off >>= 1) m = fmaxf(m, __shfl_xor(m, off));
        float ssum = 0.f;
        #pragma unroll
        for (int u = 0; u < 12; ++u) { e[u] = expf(e[u] - m); ssum += e[u]; }
        #pragma unroll
        for (int off = 32; off > 0; off >>= 1) ssum += __shfl_xor(ssum, off);
        const float inv = 1.0f / ssum;
        #pragma unroll
        for (int u = 0; u < 12; ++u) lg[h*LGS + l + u*64] = e[u] * inv;
    }
    __syncthreads();

    // ---- Phase 2: o + o_pt, A/B-pipelined global loads -------------------
    {
        float accA = 0.f;
        const float* srcA; int strA; int hA;
        if (t < 192) { srcA = v + t;          strA = 192; hA = t >> 4; }
        else         { srcA = vp + (t - 192); strA = 288; hA = (t - 192) / 24; }
        const float* arA = lg + hA * LGS;
        {
            float vA[8], vB[8];
            #pragma unroll
            for (int u = 0; u < 8; ++u) vA[u] = srcA[(size_t)u * strA];
            #pragma unroll 1
            for (int jb = 0; jb < NN; jb += 16) {
                #pragma unroll
                for (int u = 0; u < 8; ++u) vB[u] = srcA[(size_t)(jb + 8 + u) * strA];
                #pragma unroll
                for (int u = 0; u < 8; ++u) accA += arA[jb + u] * vA[u];
                if (jb + 16 < NN) {
                    #pragma unroll
                    for (int u = 0; u < 8; ++u) vA[u] = srcA[(size_t)(jb + 16 + u) * strA];
                }
                #pragma unroll
                for (int u = 0; u < 8; ++u) accA += arA[jb + 8 + u] * vB[u];
            }
        }
        float accB = 0.f;
        if (t < 224) {
            const int cB = 64 + t;                 // vp cols 64..287
            const float* srcB = vp + cB;
            const float* arB = lg + (cB / 24) * LGS;
            float vA[8], vB[8];
            #pragma unroll
            for (int u = 0; u < 8; ++u) vA[u] = srcB[(size_t)u * 288];
            #pragma unroll 1
            for (int jb = 0; jb < NN; jb += 16) {
                #pragma unroll
                for (int u = 0; u < 8; ++u) vB[u] = srcB[(size_t)(jb + 8 + u) * 288];
                #pragma unroll
                for (int u = 0; u < 8; ++u) accB += arB[jb + u] * vA[u];
                if (jb + 16 < NN) {
                    #pragma unroll
                    for (int u = 0; u < 8; ++u) vA[u] = srcB[(size_t)(jb + 16 + u) * 288];
                }
                #pragma unroll
                for (int u = 0; u < 8; ++u) accB += arB[jb + 8 + u] * vB[u];
            }
        }
        float* catr = cat + (size_t)i*CONCATn;
        if (t < 192) catr[t] = accA;
        else         pts[t - 192] = accA;
        if (t < 224) pts[64 + t] = accB;
    }
    __syncthreads();

    // ---- Phase 3: frame invert + norms -----------------------------------
    if (t < 96) {
        const float gx = pts[t*3+0] - trans[i*3+0];
        const float gy = pts[t*3+1] - trans[i*3+1];
        const float gz = pts[t*3+2] - trans[i*3+2];
        const float lx = rot[i*9+0]*gx + rot[i*9+3]*gy + rot[i*9+6]*gz;
        const float ly = rot[i*9+1]*gx + rot[i*9+4]*gy + rot[i*9+7]*gz;
        const float lz = rot[i*9+2]*gx + rot[i*9+5]*gy + rot[i*9+8]*gz;
        float* catr = cat + (size_t)i*CONCATn;
        catr[192 + t] = lx;
        catr[288 + t] = ly;
        catr[384 + t] = lz;
        catr[480 + t] = sqrtf(lx*lx + ly*ly + lz*lz + 1e-8f);
    }

    // ---- Phase 4: o_pair, A/B-pipelined float4 z + shfl ------------------
    {
        const int c4 = l & 31, jp = l >> 5;
        const float* zb = z + (size_t)i*NN*CZn + c4*4;
        const float* a0 = lg + (size_t)(3*w + 0)*LGS;
        const float* a1 = lg + (size_t)(3*w + 1)*LGS;
        const float* a2 = lg + (size_t)(3*w + 2)*LGS;
        float x00=0.f,x01=0.f,x02=0.f,x03=0.f;
        float x10=0.f,x11=0.f,x12=0.f,x13=0.f;
        float x20=0.f,x21=0.f,x22=0.f,x23=0.f;
        float4 zA[8], zB[8];
        #pragma unroll
        for (int u = 0; u < 8; ++u)
            zA[u] = *(const float4*)(zb + (size_t)(2*u + jp)*CZn);
        #pragma unroll 1
        for (int jb = 0; jb < 384; jb += 16) {
            #pragma unroll
            for (int u = 0; u < 8; ++u)
                zB[u] = *(const float4*)(zb + (size_t)(2*(jb + 8 + u) + jp)*CZn);
            #pragma unroll
            for (int u = 0; u < 8; ++u) {
                const int j = 2*(jb + u) + jp;
                const float4 zv = zA[u];
                const float A0 = a0[j], A1 = a1[j], A2 = a2[j];
                x00 += A0*zv.x; x01 += A0*zv.y; x02 += A0*zv.z; x03 += A0*zv.w;
                x10 += A1*zv.x; x11 += A1*zv.y; x12 += A1*zv.z; x13 += A1*zv.w;
                x20 += A2*zv.x; x21 += A2*zv.y; x22 += A2*zv.z; x23 += A2*zv.w;
            }
            if (jb + 16 < 384) {
                #pragma unroll
                for (int u = 0; u < 8; ++u)
                    zA[u] = *(const float4*)(zb + (size_t)(2*(jb + 16 + u) + jp)*CZn);
            }
            #pragma unroll
            for (int u = 0; u < 8; ++u) {
                const int j = 2*(jb + 8 + u) + jp;
                const float4 zv = zB[u];
                const float A0 = a0[j], A1 = a1[j], A2 = a2[j];
                x00 += A0*zv.x; x01 += A0*zv.y; x02 += A0*zv.z; x03 += A0*zv.w;
                x10 += A1*zv.x; x11 += A1*zv.y; x12 += A1*zv.z; x13 += A1*zv.w;
                x20 += A2*zv.x; x21 += A2*zv.y; x22 += A2*zv.z; x23 += A2*zv.w;
            }
        }
        x00 += __shfl_xor(x00, 32); x01 += __shfl_xor(x01, 32);
        x02 += __shfl_xor(x02, 32); x03 += __shfl_xor(x03, 32);
        x10 += __shfl_xor(x10, 32); x11 += __shfl_xor(x11, 32);
        x12 += __shfl_xor(x12, 32); x13 += __shfl_xor(x13, 32);
        x20 += __shfl_xor(x20, 32); x21 += __shfl_xor(x21, 32);
        x22 += __shfl_xor(x22, 32); x23 += __shfl_xor(x23, 32);
        if (jp == 0) {
            float* cr = cat + (size_t)i*CONCATn + 576 + c4*4;
            float4 r0; r0.x=x00; r0.y=x01; r0.z=x02; r0.w=x03;
            float4 r1; r1.x=x10; r1.y=x11; r1.z=x12; r1.w=x13;
            float4 r2; r2.x=x20; r2.y=x21; r2.z=x22; r2.w=x23;
            *(float4*)(cr + (size_t)(3*w+0)*CZn) = r0;
            *(float4*)(cr + (size_t)(3*w+1)*CZn) = r1;
            *(float4*)(cr + (size_t)(3*w+2)*CZn) = r2;
        }
    }
}

// ---------------------------------------------------------------------------
// K4: out split-K partials, 4-way + A/B-pipelined W loads.
// Grid (192 rt, 3 ot, 4 qt), 128 thr.  LDS 8.4 KB.
// ---------------------------------------------------------------------------
__global__ __launch_bounds__(128) void outpart_kernel(
    const float* __restrict__ cat, const float* __restrict__ Wout,
    float* __restrict__ pbuf)
{
    const int rt = blockIdx.x;
    const int ot = blockIdx.y;
    const int qt = blockIdx.z;
    __shared__ float cl[4 * 528];     // 8.4 KB
    const int r0 = rt * 4;
    const int kb = qt * 528;
    for (int idx = threadIdx.x; idx < 528; idx += 128) {   // 132 float4/row x 4 rows
        const int r = idx / 132, c4 = idx % 132;
        *(float4*)&cl[r*528 + c4*4] =
            *(const float4*)(cat + (size_t)(r0 + r)*CONCATn + kb + c4*4);
    }
    __syncthreads();
    const int t = threadIdx.x;
    const int r  = t >> 5;
    const int o4 = t & 31;
    const int col = ot * 128 + o4 * 4;
    float4 acc; acc.x = 0.f; acc.y = 0.f; acc.z = 0.f; acc.w = 0.f;
    const float* wp = Wout + (size_t)kb * 384 + col;
    const float* cr = cl + r * 528;
    float4 wA[8], wB[8];
    #pragma unroll
    for (int u = 0; u < 8; ++u) wA[u] = *(const float4*)(wp + (size_t)u * 384);
    #pragma unroll 1
    for (int kk = 0; kk < 528; kk += 16) {
        #pragma unroll
        for (int u = 0; u < 8; ++u)
            wB[u] = *(const float4*)(wp + (size_t)(kk + 8 + u) * 384);
        #pragma unroll
        for (int u = 0; u < 8; ++u) {
            const float cv = cr[kk + u];
            acc.x += cv * wA[u].x; acc.y += cv * wA[u].y;
            acc.z += cv * wA[u].z; acc.w += cv * wA[u].w;
        }
        if (kk + 16 < 528) {
            #pragma unroll
            for (int u = 0; u < 8; ++u)
                wA[u] = *(const float4*)(wp + (size_t)(kk + 16 + u) * 384);
        }
        #pragma unroll
        for (int u = 0; u < 8; ++u) {
            const float cv = cr[kk + 8 + u];
            acc.x += cv * wB[u].x; acc.y += cv * wB[u].y;
            acc.z += cv * wB[u].z; acc.w += cv * wB[u].w;
        }
    }
    *(float4*)(pbuf + ((size_t)qt*NN + r0 + r)*384 + col) = acc;
}

// ---------------------------------------------------------------------------
// K5: out finalize: out = p0+p1+p2+p3 + bias.  Grid 288, 256 thr, float4.
// ---------------------------------------------------------------------------
__global__ __launch_bounds__(256) void outfin_kernel(
    const float* __restrict__ pbuf, const float* __restrict__ bout,
    float* __restrict__ out)
{
    const int idx4 = blockIdx.x * 256 + threadIdx.x;   // 0..73727
    const int Q = NN * 384 / 4;                        // 73728 float4 per partial
    const float4 p0 = ((const float4*)pbuf)[idx4];
    const float4 p1 = ((const float4*)pbuf)[idx4 + Q];
    const float4 p2 = ((const float4*)pbuf)[idx4 + 2*Q];
    const float4 p3 = ((const float4*)pbuf)[idx4 + 3*Q];
    const float4 bo = *(const float4*)(bout + (idx4 % 96) * 4);
    float4 r;
    r.x = p0.x + p1.x + p2.x + p3.x + bo.x;
    r.y = p0.y + p1.y + p2.y + p3.y + bo.y;
    r.z = p0.z + p1.z + p2.z + p3.z + bo.z;
    r.w = p0.w + p1.w + p2.w + p3.w + bo.w;
    ((float4*)out)[idx4] = r;
}

// ---------------------------------------------------------------------------
extern "C" void kernel_launch(void* const* d_in, const int* in_sizes, int n_in,
                              void* d_out, int out_size, void* d_ws, size_t ws_size,
                              hipStream_t stream)
{
    const float* s     = (const float*)d_in[0];
    const float* z     = (const float*)d_in[1];
    const float* rot   = (const float*)d_in[2];
    const float* trans = (const float*)d_in[3];
    const float* mask  = (const float*)d_in[4];
    const float* Wq    = (const float*)d_in[5];
    const float* bq    = (const float*)d_in[6];
    const float* Wkv   = (const float*)d_in[7];
    const float* bkv   = (const float*)d_in[8];
    const float* Wqp   = (const float*)d_in[9];
    const float* bqp   = (const float*)d_in[10];
    const float* Wkvp  = (const float*)d_in[11];
    const float* bkvp  = (const float*)d_in[12];
    const float* Wb    = (const float*)d_in[13];
    const float* bb    = (const float*)d_in[14];
    const float* head_w= (const float*)d_in[15];
    const float* Wout  = (const float*)d_in[16];
    const float* bout  = (const float*)d_in[17];
    float* out = (float*)d_out;

    float* ws    = (float*)d_ws;
    float* q     = ws;                  // 147456  [N][192]
    float* kT    = q     + 147456;      // 147456  [192][N]
    float* qp    = kT    + 147456;      // 110592  [N][144]
    float* kpT   = qp    + 110592;      // 110592  [144][N]
    float* v     = kpT   + 110592;      // 147456  [N][192]
    float* vp    = v     + 147456;      // 221184  [N][288]
    float* cat   = vp    + 221184;      // 1622016
    float* linG  = cat   + 1622016;     // 884736
    float* bG    = linG  + 884736;      // 7077888 (28 MB)
    float* pbuf  = bG    + 7077888;     // 1179648 (4x out partials)

    hipLaunchKernelGGL(projbias_kernel, dim3(864 + 12*768), dim3(256), 0, stream,
        s, Wq, bq, Wkv, bkv, Wqp, bqp, Wkvp, bkvp, linG, z, Wb, bb, bG);
    hipLaunchKernelGGL(scatter_kernel, dim3(768), dim3(256), 0, stream,
        linG, rot, trans, q, kT, v, qp, kpT, vp);
    hipLaunchKernelGGL(mega_kernel, dim3(768), dim3(256), 0, stream,
        mask, q, qp, kT, kpT, bG, head_w, z, v, vp, rot, trans, cat);
    hipLaunchKernelGGL(outpart_kernel, dim3(192, 3, 4), dim3(128), 0, stream,
        cat, Wout, pbuf);
    hipLaunchKernelGGL(outfin_kernel, dim3(288), dim3(256), 0, stream,
        pbuf, bout, out);
}